// Round 5
// baseline (332.489 us; speedup 1.0000x reference)
//
#include <hip/hip_runtime.h>
#include <cmath>

// Problem constants
#define NROWS 800        // BS*NQ
#define NCLS  81
#define MT    160        // targets
#define PPX   65536      // pixels per mask
#define SSPLIT 32        // K splits
#define CHUNK 2048       // PPX / SSPLIT
#define BK    64         // K per iteration
#define ITERS (CHUNK / BK)   // 32
#define RPB   32         // rows per block
#define RB    25         // row blocks (25*32 = 800 exact)

// Workspace layout (bytes)
#define OFF_TBF   0
#define SZ_TBF    (MT * PPX * 2)                 // 20,971,520 (bf16, natural row-major)
#define OFF_CROSS (SZ_TBF)
#define OFF_SDOT  (OFF_CROSS + NROWS * MT * 4)
#define OFF_ROW   (OFF_SDOT + NROWS * MT * 4)
#define OFF_SSUM  (OFF_ROW + NROWS * 4)
#define OFF_TSUM  (OFF_SSUM + NROWS * 4)
#define OFF_PROB  (OFF_TSUM + MT * 4)
#define OFF_END   (OFF_PROB + NROWS * NCLS * 4)

typedef __attribute__((ext_vector_type(8))) short bf16x8;
typedef __attribute__((ext_vector_type(4))) float f32x4;

__device__ __forceinline__ unsigned short f2bf(float f) {
    unsigned int u = __float_as_uint(f);
    unsigned int r = (u + 0x7FFFu + ((u >> 16) & 1u)) >> 16;   // RNE
    return (unsigned short)r;
}

// ---------------------------------------------------------------------------
// Kernel 1: tgt_mask fp32 -> bf16 (natural layout) + exact tsum[m].
// Grid: 5120 x 256. Each thread: 8 consecutive pixels. Whole block = one m.
// ---------------------------------------------------------------------------
__global__ __launch_bounds__(256) void prep_kernel(const float* __restrict__ tgt_mask,
                                                   char* __restrict__ ws) {
    int g = blockIdx.x * 256 + threadIdx.x;
    int m = g >> 13;            // 8192 8-px chunks per row
    int kc = g & 8191;
    const float4* src = (const float4*)(tgt_mask + (size_t)m * PPX + (kc << 3));
    float4 a = src[0], b = src[1];
    float part = a.x + a.y + a.z + a.w + b.x + b.y + b.z + b.w;

    uint4 o;
    o.x = (unsigned)f2bf(a.x) | ((unsigned)f2bf(a.y) << 16);
    o.y = (unsigned)f2bf(a.z) | ((unsigned)f2bf(a.w) << 16);
    o.z = (unsigned)f2bf(b.x) | ((unsigned)f2bf(b.y) << 16);
    o.w = (unsigned)f2bf(b.z) | ((unsigned)f2bf(b.w) << 16);
    *(uint4*)(ws + OFF_TBF + (size_t)m * (PPX * 2) + (size_t)kc * 16) = o;

    #pragma unroll
    for (int mk = 32; mk; mk >>= 1) part += __shfl_xor(part, mk);
    __shared__ float wsum[4];
    if ((threadIdx.x & 63) == 0) wsum[threadIdx.x >> 6] = part;
    __syncthreads();
    if (threadIdx.x == 0) {
        float tot = wsum[0] + wsum[1] + wsum[2] + wsum[3];
        atomicAdd((float*)(ws + OFF_TSUM) + m, tot);
    }
}

// ---------------------------------------------------------------------------
// Kernel 2: row softmax of pred_logits -> prob[800][81]
// ---------------------------------------------------------------------------
__global__ __launch_bounds__(64) void softmax_kernel(const float* __restrict__ logits,
                                                     float* __restrict__ prob) {
    int n = blockIdx.x;
    int l = threadIdx.x;
    const float* row = logits + n * NCLS;
    float v0 = row[l];
    float v1 = (l + 64 < NCLS) ? row[l + 64] : -INFINITY;
    float mx = fmaxf(v0, v1);
    #pragma unroll
    for (int mk = 32; mk; mk >>= 1) mx = fmaxf(mx, __shfl_xor(mx, mk));
    float e0 = __expf(v0 - mx);
    float e1 = (l + 64 < NCLS) ? __expf(v1 - mx) : 0.f;
    float s = e0 + e1;
    #pragma unroll
    for (int mk = 32; mk; mk >>= 1) s += __shfl_xor(s, mk);
    float inv = 1.f / s;
    prob[n * NCLS + l] = e0 * inv;
    if (l + 64 < NCLS) prob[n * NCLS + l + 64] = e1 * inv;
}

// ---------------------------------------------------------------------------
// Kernel 3: fused elementwise + dual GEMM (split-K), NO LDS / NO BARRIERS.
// Block: 256 threads (4 waves), each wave an independent 16x80 output tile:
//   wr = w&1 (row half), wc = w>>1 (col half). Fragments are lane-local:
//   A: lane loads x[row=base+（l&15)][px=(l>>4)*8..] directly (fp32->bf16);
//   B: lane loads t_bf16[col-row][same px] (natural layout, L2-resident/XCD).
// x prefetch depth = 2 iterations (ping-pong XA/XB register sets).
// ---------------------------------------------------------------------------
struct XS { float4 a0, a1, b0, b1; };   // kk0: a0,a1  kk1: b0,b1

__device__ __forceinline__ void loadx(XS& x, const float* xrow, int it) {
    const float* p = xrow + it * BK;
    x.a0 = *(const float4*)(p);
    x.a1 = *(const float4*)(p + 4);
    x.b0 = *(const float4*)(p + 32);
    x.b1 = *(const float4*)(p + 36);
}

__device__ __forceinline__ void ew8(const float4& u, const float4& v,
                                    bf16x8& xv, bf16x8& sv,
                                    float& sp_acc, float& sg_acc, bool count) {
    float vals[8] = {u.x, u.y, u.z, u.w, v.x, v.y, v.z, v.w};
    #pragma unroll
    for (int j = 0; j < 8; ++j) {
        float t = vals[j];
        float av = fabsf(t);
        float e = __expf(-av);
        float t1 = 1.f + e;
        float r = __builtin_amdgcn_rcpf(t1);
        float sg = (t >= 0.f) ? r : e * r;
        if (count) {                       // wave-uniform branch
            sg_acc += sg;
            sp_acc += fmaxf(t, 0.f) + __logf(t1);
        }
        xv[j] = (short)f2bf(t);
        sv[j] = (short)f2bf(sg);
    }
}

__global__ __launch_bounds__(256) void main_kernel(const float* __restrict__ pred_masks,
                                                   char* __restrict__ ws) {
    const int tid = threadIdx.x;
    const int w = tid >> 6, l = tid & 63;
    const int rb = blockIdx.x >> 5;
    const int s = blockIdx.x & 31;       // bid%8 = s%8 -> same-s blocks share XCD L2
    const int k_base = s * CHUNK;

    const int wr = w & 1, wc = w >> 1;
    const int lrow = l & 15;             // fragment row index
    const int lk = l >> 4;               // k-chunk 0..3

    const float* xrow = pred_masks + (size_t)(rb * RPB + wr * 16 + lrow) * PPX
                      + k_base + lk * 8;
    const unsigned short* tb = (const unsigned short*)(ws + OFF_TBF);
    const unsigned short* tptr[5];
    #pragma unroll
    for (int cf = 0; cf < 5; ++cf)
        tptr[cf] = tb + (size_t)(wc * 80 + cf * 16 + lrow) * PPX + k_base + lk * 8;

    f32x4 accX[5], accS[5];
    #pragma unroll
    for (int i = 0; i < 5; ++i) { accX[i] = (f32x4)(0.f); accS[i] = (f32x4)(0.f); }
    float rs_sp = 0.f, rs_sg = 0.f;
    const bool cnt0 = (wc == 0), cnt1 = (wc == 1);

    XS XA, XB;
    loadx(XA, xrow, 0);
    loadx(XB, xrow, 1);

    #pragma unroll 1
    for (int it = 0; it < ITERS; it += 2) {
        // ---------------- even step: consume XA (iter it) ----------------
        {
            bf16x8 bt[2][5];
            #pragma unroll
            for (int kk = 0; kk < 2; ++kk)
                #pragma unroll
                for (int cf = 0; cf < 5; ++cf)
                    bt[kk][cf] = *(const bf16x8*)(tptr[cf] + it * BK + kk * 32);

            bf16x8 ax0, as0, ax1, as1;
            ew8(XA.a0, XA.a1, ax0, as0, rs_sp, rs_sg, cnt0);
            ew8(XA.b0, XA.b1, ax1, as1, rs_sp, rs_sg, cnt1);

            int itn = it + 2;                       // prefetch 2 ahead
            loadx(XA, xrow, itn < ITERS ? itn : ITERS - 1);

            #pragma unroll
            for (int cf = 0; cf < 5; ++cf) {
                accX[cf] = __builtin_amdgcn_mfma_f32_16x16x32_bf16(ax0, bt[0][cf], accX[cf], 0, 0, 0);
                accS[cf] = __builtin_amdgcn_mfma_f32_16x16x32_bf16(as0, bt[0][cf], accS[cf], 0, 0, 0);
                accX[cf] = __builtin_amdgcn_mfma_f32_16x16x32_bf16(ax1, bt[1][cf], accX[cf], 0, 0, 0);
                accS[cf] = __builtin_amdgcn_mfma_f32_16x16x32_bf16(as1, bt[1][cf], accS[cf], 0, 0, 0);
            }
        }
        // ---------------- odd step: consume XB (iter it+1) ----------------
        {
            int itc = it + 1;
            bf16x8 bt[2][5];
            #pragma unroll
            for (int kk = 0; kk < 2; ++kk)
                #pragma unroll
                for (int cf = 0; cf < 5; ++cf)
                    bt[kk][cf] = *(const bf16x8*)(tptr[cf] + itc * BK + kk * 32);

            bf16x8 ax0, as0, ax1, as1;
            ew8(XB.a0, XB.a1, ax0, as0, rs_sp, rs_sg, cnt0);
            ew8(XB.b0, XB.b1, ax1, as1, rs_sp, rs_sg, cnt1);

            int itn = itc + 2;
            loadx(XB, xrow, itn < ITERS ? itn : ITERS - 1);

            #pragma unroll
            for (int cf = 0; cf < 5; ++cf) {
                accX[cf] = __builtin_amdgcn_mfma_f32_16x16x32_bf16(ax0, bt[0][cf], accX[cf], 0, 0, 0);
                accS[cf] = __builtin_amdgcn_mfma_f32_16x16x32_bf16(as0, bt[0][cf], accS[cf], 0, 0, 0);
                accX[cf] = __builtin_amdgcn_mfma_f32_16x16x32_bf16(ax1, bt[1][cf], accX[cf], 0, 0, 0);
                accS[cf] = __builtin_amdgcn_mfma_f32_16x16x32_bf16(as1, bt[1][cf], accS[cf], 0, 0, 0);
            }
        }
    }

    // ---- row sums: lanes l, l^16, l^32, l^48 share a row
    rs_sp += __shfl_xor(rs_sp, 16); rs_sp += __shfl_xor(rs_sp, 32);
    rs_sg += __shfl_xor(rs_sg, 16); rs_sg += __shfl_xor(rs_sg, 32);
    float* acc_row = (float*)(ws + OFF_ROW);
    float* acc_ssum = (float*)(ws + OFF_SSUM);
    if (l < 16) {
        int n = rb * RPB + wr * 16 + l;
        atomicAdd(acc_row + n, rs_sp);
        atomicAdd(acc_ssum + n, rs_sg);
    }

    // ---- split-K accumulate the C fragments
    float* acc_cross = (float*)(ws + OFF_CROSS);
    float* acc_sdot = (float*)(ws + OFF_SDOT);
    #pragma unroll
    for (int cf = 0; cf < 5; ++cf) {
        int mcol = wc * 80 + cf * 16 + lrow;
        #pragma unroll
        for (int i = 0; i < 4; ++i) {
            int nrow = rb * RPB + wr * 16 + lk * 4 + i;
            atomicAdd(acc_cross + nrow * MT + mcol, accX[cf][i]);
            atomicAdd(acc_sdot + nrow * MT + mcol, accS[cf][i]);
        }
    }
}

// ---------------------------------------------------------------------------
// Kernel 4: combine into C[n][m]
// ---------------------------------------------------------------------------
__global__ __launch_bounds__(256) void final_kernel(const int* __restrict__ tgt_ids,
                                                    const char* __restrict__ ws,
                                                    float* __restrict__ out) {
    int idx = blockIdx.x * 256 + threadIdx.x;   // 0..127999
    int n = idx / MT;
    int m = idx - n * MT;
    const float* prob = (const float*)(ws + OFF_PROB);
    const float* acc_cross = (const float*)(ws + OFF_CROSS);
    const float* acc_sdot = (const float*)(ws + OFF_SDOT);
    const float* acc_row = (const float*)(ws + OFF_ROW);
    const float* acc_ssum = (const float*)(ws + OFF_SSUM);
    const float* tsum = (const float*)(ws + OFF_TSUM);

    float cls = -prob[n * NCLS + tgt_ids[m]];
    float cmask = (acc_row[n] - acc_cross[idx]) * (1.f / PPX);
    float cdice = 1.f - (2.f * acc_sdot[idx] + 1.f) / (acc_ssum[n] + tsum[m] + 1.f);
    out[idx] = cls + cmask + cdice;
}

extern "C" void kernel_launch(void* const* d_in, const int* in_sizes, int n_in,
                              void* d_out, int out_size, void* d_ws, size_t ws_size,
                              hipStream_t stream) {
    const float* pred_logits = (const float*)d_in[0];
    const float* pred_masks  = (const float*)d_in[1];
    const int*   tgt_ids     = (const int*)d_in[2];
    const float* tgt_mask    = (const float*)d_in[3];
    char* ws = (char*)d_ws;

    hipMemsetAsync(ws + OFF_CROSS, 0, OFF_END - OFF_CROSS, stream);
    prep_kernel<<<5120, 256, 0, stream>>>(tgt_mask, ws);
    softmax_kernel<<<NROWS, 64, 0, stream>>>(pred_logits, (float*)(ws + OFF_PROB));
    main_kernel<<<RB * SSPLIT, 256, 0, stream>>>(pred_masks, ws);
    final_kernel<<<500, 256, 0, stream>>>(tgt_ids, ws, (float*)d_out);
}

// Round 8
// 137.419 us; speedup vs baseline: 2.4195x; 2.4195x over previous
//
#include <hip/hip_runtime.h>
#include <cmath>

// Problem constants
#define NROWS 800        // BS*NQ
#define NCLS  81
#define MT    160        // targets
#define PPX   65536      // pixels per mask
#define SSPLIT 32        // K splits
#define CHUNK 2048       // PPX / SSPLIT
#define BK    64         // K per iteration
#define ITERS (CHUNK / BK)   // 32
#define RPB   32         // rows per block
#define RB    25         // row blocks (25*32 = 800 exact)

// Workspace layout (bytes)
#define OFF_TBF   0
#define SZ_TBF    (MT * PPX * 2)                 // 20,971,520 (bf16, pre-swizzled)
#define OFF_CROSS (SZ_TBF)
#define OFF_SDOT  (OFF_CROSS + NROWS * MT * 4)
#define OFF_ROW   (OFF_SDOT + NROWS * MT * 4)
#define OFF_SSUM  (OFF_ROW + NROWS * 4)
#define OFF_TSUM  (OFF_SSUM + NROWS * 4)
#define OFF_PROB  (OFF_TSUM + MT * 4)
#define OFF_END   (OFF_PROB + NROWS * NCLS * 4)

typedef __attribute__((ext_vector_type(8))) short bf16x8;
typedef __attribute__((ext_vector_type(4))) float f32x4;

typedef __attribute__((address_space(3))) char lds_char;
typedef const __attribute__((address_space(1))) char glob_char;

__device__ __forceinline__ unsigned short f2bf(float f) {
    unsigned int u = __float_as_uint(f);
    unsigned int r = (u + 0x7FFFu + ((u >> 16) & 1u)) >> 16;   // RNE
    return (unsigned short)r;
}

// ---------------------------------------------------------------------------
// Kernel 1: tgt_mask fp32 -> bf16, PRE-SWIZZLED (chunk c of row m at slot
// c^(m&7)) so linear global_load_lds gives a conflict-free LDS tile. + tsum.
// ---------------------------------------------------------------------------
__global__ __launch_bounds__(256) void prep_kernel(const float* __restrict__ tgt_mask,
                                                   char* __restrict__ ws) {
    int g = blockIdx.x * 256 + threadIdx.x;
    int m = g >> 13;            // 8192 8-px chunks per row
    int kc = g & 8191;
    const float4* src = (const float4*)(tgt_mask + (size_t)m * PPX + (kc << 3));
    float4 a = src[0], b = src[1];
    float part = a.x + a.y + a.z + a.w + b.x + b.y + b.z + b.w;

    uint4 o;
    o.x = (unsigned)f2bf(a.x) | ((unsigned)f2bf(a.y) << 16);
    o.y = (unsigned)f2bf(a.z) | ((unsigned)f2bf(a.w) << 16);
    o.z = (unsigned)f2bf(b.x) | ((unsigned)f2bf(b.y) << 16);
    o.w = (unsigned)f2bf(b.z) | ((unsigned)f2bf(b.w) << 16);

    int group = kc >> 3;                 // 64-px group index
    int c = kc & 7;                      // 16B chunk within group
    int oc = (group << 3) | (c ^ (m & 7));   // swizzled chunk slot
    *(uint4*)(ws + OFF_TBF + (size_t)m * (PPX * 2) + (size_t)oc * 16) = o;

    #pragma unroll
    for (int mk = 32; mk; mk >>= 1) part += __shfl_xor(part, mk);
    __shared__ float wsum[4];
    if ((threadIdx.x & 63) == 0) wsum[threadIdx.x >> 6] = part;
    __syncthreads();
    if (threadIdx.x == 0) {
        float tot = wsum[0] + wsum[1] + wsum[2] + wsum[3];
        atomicAdd((float*)(ws + OFF_TSUM) + m, tot);
    }
}

// ---------------------------------------------------------------------------
// Kernel 2: row softmax of pred_logits -> prob[800][81]
// ---------------------------------------------------------------------------
__global__ __launch_bounds__(64) void softmax_kernel(const float* __restrict__ logits,
                                                     float* __restrict__ prob) {
    int n = blockIdx.x;
    int l = threadIdx.x;
    const float* row = logits + n * NCLS;
    float v0 = row[l];
    float v1 = (l + 64 < NCLS) ? row[l + 64] : -INFINITY;
    float mx = fmaxf(v0, v1);
    #pragma unroll
    for (int mk = 32; mk; mk >>= 1) mx = fmaxf(mx, __shfl_xor(mx, mk));
    float e0 = __expf(v0 - mx);
    float e1 = (l + 64 < NCLS) ? __expf(v1 - mx) : 0.f;
    float s = e0 + e1;
    #pragma unroll
    for (int mk = 32; mk; mk >>= 1) s += __shfl_xor(s, mk);
    float inv = 1.f / s;
    prob[n * NCLS + l] = e0 * inv;
    if (l + 64 < NCLS) prob[n * NCLS + l + 64] = e1 * inv;
}

// ---------------------------------------------------------------------------
// Kernel 3: fused elementwise + dual GEMM (split-K).
// Pipeline: lds_t DOUBLE-buffered (tile h+1 staged during half h), x register
// prefetch depth-2 (XA/XB ping-pong, refill 2 tiles ahead). Barrier waits
// s_waitcnt vmcnt(9): everything except {refill(h-1),stage(h+1),refill(h)}
// = 2+5+2 = 9 newest vmem ops retired -> tile h's glld complete, x refills
// stay in flight across the barrier. Never vmcnt(0) in the loop.
// ---------------------------------------------------------------------------
struct XS { float4 a; float4 b; };      // one iteration's 8 px (fp32)

__device__ __forceinline__ void loadx(XS& x, const float* xrow, int it) {
    const float* p = xrow + it * BK;
    x.a = *(const float4*)(p);
    x.b = *(const float4*)(p + 4);
}

// 8 px: e^v via exp2, sigmoid = t2/(1+t2), softplus accumulated in log2 units.
__device__ __forceinline__ void ew8(const XS& xs, bf16x8& xv, bf16x8& sv,
                                    float& slog2, float& sg_acc) {
    float vals[8] = {xs.a.x, xs.a.y, xs.a.z, xs.a.w, xs.b.x, xs.b.y, xs.b.z, xs.b.w};
    #pragma unroll
    for (int j = 0; j < 8; ++j) {
        float v = vals[j];
        float vl = fminf(v * 1.44269504089f, 126.f);         // overflow clamp
        float t2 = __builtin_amdgcn_exp2f(vl);               // e^v
        float d = 1.f + t2;
        float r = __builtin_amdgcn_rcpf(d);
        float sg = t2 * r;                                   // sigmoid(v)
        slog2 += __builtin_amdgcn_logf(d);                   // log2(1+e^v)
        sg_acc += sg;
        xv[j] = (short)f2bf(v);
        sv[j] = (short)f2bf(sg);
    }
}

__global__ __launch_bounds__(256) void main_kernel(const float* __restrict__ pred_masks,
                                                   char* __restrict__ ws) {
    __shared__ __align__(16) unsigned short lds_t[2][MT * BK]; // 2x20480 B
    __shared__ __align__(16) unsigned short lds_x[RPB * BK];   //  4096 B
    __shared__ __align__(16) unsigned short lds_s[RPB * BK];   //  4096 B

    const int tid = threadIdx.x;
    const int w = tid >> 6, l = tid & 63;
    const int rb = blockIdx.x >> 5;
    const int s = blockIdx.x & 31;       // bid%8 = s%8 -> same-s blocks share XCD L2
    const int k_base = s * CHUNK;

    // ---- x staging coords (thread: 1 row, 8 consecutive pixels)
    const int srow = tid >> 3;           // 0..31
    const int sc8 = tid & 7;             // 16B chunk within 64-px row
    const int n_glob = rb * RPB + srow;
    const float* xrow = pred_masks + (size_t)n_glob * PPX + k_base + sc8 * 8;
    char* xw = (char*)lds_x + srow * 128 + ((sc8 ^ (srow & 7)) * 16);
    char* swp = (char*)lds_s + srow * 128 + ((sc8 ^ (srow & 7)) * 16);

    const char* tbase = ws + OFF_TBF;

    // stage 5x8 t-rows (one wave: 40 rows) of tile tt into LDS buffer b
    auto stage_t = [&](int b, int tt) {
        const int k0 = k_base + tt * BK;
        #pragma unroll
        for (int i = 0; i < 5; ++i) {
            int rows_base = w * 40 + i * 8;
            const char* g = (const char*)tbase
                          + (size_t)(rows_base + (l >> 3)) * (PPX * 2)
                          + (size_t)k0 * 2 + (size_t)(l & 7) * 16;
            __builtin_amdgcn_global_load_lds((glob_char*)g,
                                             (lds_char*)((char*)lds_t[b] + rows_base * 128),
                                             16, 0, 0);
        }
    };

    const int wr = w & 1, wc = w >> 1;   // wave: 16-row half x 80-col half
    f32x4 accX[5], accS[5];
    #pragma unroll
    for (int i = 0; i < 5; ++i) { accX[i] = (f32x4)(0.f); accS[i] = (f32x4)(0.f); }
    float slog2 = 0.f, rs_sg = 0.f;

    // prologue: tile 0 -> buf0; x tiles 0,1 -> XA,XB
    stage_t(0, 0);
    XS XA, XB;
    loadx(XA, xrow, 0);
    loadx(XB, xrow, 1);

    #pragma unroll 1
    for (int it = 0; it < ITERS; it += 2) {
        #pragma unroll
        for (int half = 0; half < 2; ++half) {
            const int h = it + half;         // tile being computed
            const int hb = half;             // its buffer (h&1 == half)

            // stage tile h+1 into the other buffer (clamped dup at tail)
            int tn = h + 1; if (tn >= ITERS) tn = ITERS - 1;
            stage_t(hb ^ 1, tn);
            __builtin_amdgcn_sched_barrier(0);

            // elementwise on the prefetched regs, write bf16 to LDS
            bf16x8 xv, sv;
            if (half == 0) ew8(XA, xv, sv, slog2, rs_sg);
            else           ew8(XB, xv, sv, slog2, rs_sg);
            *(bf16x8*)xw = xv;
            *(bf16x8*)swp = sv;

            // refill the just-consumed register set, 2 tiles ahead
            int tr = h + 2; if (tr >= ITERS) tr = ITERS - 1;
            if (half == 0) loadx(XA, xrow, tr);
            else           loadx(XB, xrow, tr);

            // tile h's glld (issued last half) retired; 9 newer vmem ops
            // ({refill h-1}2 + {stage h+1}5 + {refill h}2) may stay in flight
            asm volatile("s_waitcnt vmcnt(9) lgkmcnt(0)" ::: "memory");
            __builtin_amdgcn_sched_barrier(0);
            __builtin_amdgcn_s_barrier();
            __builtin_amdgcn_sched_barrier(0);

            // MFMA: per wave 16 rows x 80 cols, K=64 in two k-steps
            #pragma unroll
            for (int kk = 0; kk < 2; ++kk) {
                int arow = wr * 16 + (l & 15);
                int achunk = (kk * 4 + (l >> 4)) ^ (arow & 7);
                bf16x8 ax = *(bf16x8*)((char*)lds_x + arow * 128 + achunk * 16);
                bf16x8 as = *(bf16x8*)((char*)lds_s + arow * 128 + achunk * 16);
                #pragma unroll
                for (int cf = 0; cf < 5; ++cf) {
                    int mrow = (wc * 5 + cf) * 16 + (l & 15);
                    int bchunk = (kk * 4 + (l >> 4)) ^ (mrow & 7);
                    bf16x8 bv = *(bf16x8*)((char*)lds_t[hb] + mrow * 128 + bchunk * 16);
                    accX[cf] = __builtin_amdgcn_mfma_f32_16x16x32_bf16(ax, bv, accX[cf], 0, 0, 0);
                    accS[cf] = __builtin_amdgcn_mfma_f32_16x16x32_bf16(as, bv, accS[cf], 0, 0, 0);
                }
            }

            // LDS reads done before next half overwrites lds_x/lds_s (WAR)
            asm volatile("s_waitcnt lgkmcnt(0)" ::: "memory");
            __builtin_amdgcn_sched_barrier(0);
            __builtin_amdgcn_s_barrier();
            __builtin_amdgcn_sched_barrier(0);
        }
    }

    // drain any pending vmem (tail stage/refill) before epilogue
    asm volatile("s_waitcnt vmcnt(0)" ::: "memory");

    // ---- row sums: reduce over the 8 lanes sharing a row, one atomic each
    float rs_sp = slog2 * 0.69314718056f;
    rs_sp += __shfl_xor(rs_sp, 1); rs_sp += __shfl_xor(rs_sp, 2); rs_sp += __shfl_xor(rs_sp, 4);
    rs_sg += __shfl_xor(rs_sg, 1); rs_sg += __shfl_xor(rs_sg, 2); rs_sg += __shfl_xor(rs_sg, 4);
    float* acc_row = (float*)(ws + OFF_ROW);
    float* acc_ssum = (float*)(ws + OFF_SSUM);
    if ((tid & 7) == 0) {
        atomicAdd(acc_row + n_glob, rs_sp);
        atomicAdd(acc_ssum + n_glob, rs_sg);
    }

    // ---- split-K accumulate the C fragments
    float* acc_cross = (float*)(ws + OFF_CROSS);
    float* acc_sdot = (float*)(ws + OFF_SDOT);
    #pragma unroll
    for (int cf = 0; cf < 5; ++cf) {
        int mcol = (wc * 5 + cf) * 16 + (l & 15);
        #pragma unroll
        for (int i = 0; i < 4; ++i) {
            int nrow = rb * RPB + wr * 16 + (l >> 4) * 4 + i;
            atomicAdd(acc_cross + nrow * MT + mcol, accX[cf][i]);
            atomicAdd(acc_sdot + nrow * MT + mcol, accS[cf][i]);
        }
    }
}

// ---------------------------------------------------------------------------
// Kernel 4: combine into C[n][m]
// ---------------------------------------------------------------------------
__global__ __launch_bounds__(256) void final_kernel(const int* __restrict__ tgt_ids,
                                                    const char* __restrict__ ws,
                                                    float* __restrict__ out) {
    int idx = blockIdx.x * 256 + threadIdx.x;   // 0..127999
    int n = idx / MT;
    int m = idx - n * MT;
    const float* prob = (const float*)(ws + OFF_PROB);
    const float* acc_cross = (const float*)(ws + OFF_CROSS);
    const float* acc_sdot = (const float*)(ws + OFF_SDOT);
    const float* acc_row = (const float*)(ws + OFF_ROW);
    const float* acc_ssum = (const float*)(ws + OFF_SSUM);
    const float* tsum = (const float*)(ws + OFF_TSUM);

    float cls = -prob[n * NCLS + tgt_ids[m]];
    float cmask = (acc_row[n] - acc_cross[idx]) * (1.f / PPX);
    float cdice = 1.f - (2.f * acc_sdot[idx] + 1.f) / (acc_ssum[n] + tsum[m] + 1.f);
    out[idx] = cls + cmask + cdice;
}

extern "C" void kernel_launch(void* const* d_in, const int* in_sizes, int n_in,
                              void* d_out, int out_size, void* d_ws, size_t ws_size,
                              hipStream_t stream) {
    const float* pred_logits = (const float*)d_in[0];
    const float* pred_masks  = (const float*)d_in[1];
    const int*   tgt_ids     = (const int*)d_in[2];
    const float* tgt_mask    = (const float*)d_in[3];
    char* ws = (char*)d_ws;

    (void)hipMemsetAsync(ws + OFF_CROSS, 0, OFF_END - OFF_CROSS, stream);
    prep_kernel<<<5120, 256, 0, stream>>>(tgt_mask, ws);
    softmax_kernel<<<NROWS, 64, 0, stream>>>(pred_logits, (float*)(ws + OFF_PROB));
    main_kernel<<<RB * SSPLIT, 256, 0, stream>>>(pred_masks, ws);
    final_kernel<<<500, 256, 0, stream>>>(tgt_ids, ws, (float*)d_out);
}